// Round 16
// baseline (398.905 us; speedup 1.0000x reference)
//
#include <hip/hip_runtime.h>
#include <hip/hip_bf16.h>

constexpr int B_ = 16;
constexpr int S_ = 2048;
constexpr int D_ = 1024;
constexpr int C_ = 1280;                              // compacted K capacity (5*256)
constexpr long long BSD = (long long)B_ * S_ * D_;   // 33,554,432

typedef unsigned short u16;
typedef __bf16 bf16x8 __attribute__((ext_vector_type(8)));
typedef float    f32x4 __attribute__((ext_vector_type(4)));
typedef unsigned short usx8 __attribute__((ext_vector_type(8)));
typedef unsigned short usx4 __attribute__((ext_vector_type(4)));

__device__ inline u16 f2b(float f) {            // f32 -> bf16 RNE
  unsigned u = __float_as_uint(f);
  u = (u + 0x7fffu + ((u >> 16) & 1u)) >> 16;
  return (u16)u;
}
__device__ inline float b2f(u16 v) { return __uint_as_float(((unsigned)v) << 16); }

__device__ __forceinline__ void gll16(const void* g, void* l) {
  __builtin_amdgcn_global_load_lds(
      (const __attribute__((address_space(1))) void*)g,
      (__attribute__((address_space(3))) void*)l, 16, 0, 0);
}

__device__ __forceinline__ void vmwait6() {
  asm volatile("s_waitcnt vmcnt(6)" ::: "memory");
  __builtin_amdgcn_sched_barrier(0);
}
__device__ __forceinline__ void vmwait2() {
  asm volatile("s_waitcnt vmcnt(2)" ::: "memory");
  __builtin_amdgcn_sched_barrier(0);
}
__device__ __forceinline__ void vmwait0() {
  asm volatile("s_waitcnt vmcnt(0)" ::: "memory");
  __builtin_amdgcn_sched_barrier(0);
}
__device__ __forceinline__ void lgkm10() {
  asm volatile("s_waitcnt lgkmcnt(10)" ::: "memory");
  __builtin_amdgcn_sched_barrier(0);
}
__device__ __forceinline__ void lgkm4() {
  asm volatile("s_waitcnt lgkmcnt(4)" ::: "memory");
  __builtin_amdgcn_sched_barrier(0);
}
__device__ __forceinline__ void lgkm2() {
  asm volatile("s_waitcnt lgkmcnt(2)" ::: "memory");
  __builtin_amdgcn_sched_barrier(0);
}
__device__ __forceinline__ void lgkm0w() {
  asm volatile("s_waitcnt lgkmcnt(0)" ::: "memory");
  __builtin_amdgcn_sched_barrier(0);
}
__device__ __forceinline__ void sbar() { __builtin_amdgcn_sched_barrier(0); }
__device__ __forceinline__ void barrier_pin() {
  __builtin_amdgcn_sched_barrier(0);
  __builtin_amdgcn_s_barrier();
  __builtin_amdgcn_sched_barrier(0);
}

// ---------------- fused prep: X cvt (16384), W transpose+cvt (3072),
// bias pack (1), per-batch mask compaction scan (16) ----------------
__global__ __launch_bounds__(256) void k_prep(
    const float* __restrict__ X, u16* __restrict__ Xb,
    const float* __restrict__ Wq, const float* __restrict__ Wk, const float* __restrict__ Wv,
    const float* __restrict__ bq, const float* __restrict__ bk, const float* __restrict__ bv,
    const int* __restrict__ mask, u16* __restrict__ Wt,
    float* __restrict__ biasQKV, int* __restrict__ map, int* __restrict__ counts) {
  __shared__ float tile[32][33];
  __shared__ int ts[256];
  const int bid = blockIdx.x;
  const int tid = threadIdx.x;
  if (bid < 16384) {
    size_t i = ((size_t)bid * 256 + tid) * 8;
    f32x4 a = *(const f32x4*)(X + i);
    f32x4 b = *(const f32x4*)(X + i + 4);
    usx8 o;
    o[0] = f2b(a[0]); o[1] = f2b(a[1]); o[2] = f2b(a[2]); o[3] = f2b(a[3]);
    o[4] = f2b(b[0]); o[5] = f2b(b[1]); o[6] = f2b(b[2]); o[7] = f2b(b[3]);
    *(usx8*)(Xb + i) = o;
  } else if (bid < 16384 + 3072) {
    const int wb = bid - 16384;
    const int z = wb >> 10, t = wb & 1023;
    const float* W = (z == 0) ? Wq : (z == 1 ? Wk : Wv);
    u16* dst = Wt + (size_t)z * D_ * D_;
    const int n0 = (t & 31) * 32, k0 = (t >> 5) * 32;
    const int tx = tid & 31, ty = tid >> 5;
    for (int r = ty; r < 32; r += 8)
      tile[r][tx] = W[(size_t)(k0 + r) * D_ + n0 + tx];
    __syncthreads();
    for (int r = ty; r < 32; r += 8)
      dst[(size_t)(n0 + r) * D_ + k0 + tx] = f2b(tile[tx][r]);
  } else if (bid == 16384 + 3072) {
    for (int x = tid; x < 3072; x += 256)
      biasQKV[x] = (x < 1024) ? bq[x] : (x < 2048 ? bk[x - 1024] : bv[x - 2048]);
  } else {
    const int b = bid - (16384 + 3073);
    const int* mrow = mask + b * S_;
    int lv[8]; int s = 0;
#pragma unroll
    for (int j = 0; j < 8; ++j) { lv[j] = (mrow[tid * 8 + j] != 0) ? 1 : 0; s += lv[j]; }
    ts[tid] = s;
    __syncthreads();
    for (int off = 1; off < 256; off <<= 1) {
      int v = (tid >= off) ? ts[tid - off] : 0;
      __syncthreads();
      ts[tid] += v;
      __syncthreads();
    }
    int pos = ts[tid] - s;                        // exclusive prefix
#pragma unroll
    for (int j = 0; j < 8; ++j) if (lv[j]) map[b * C_ + (pos++)] = tid * 8 + j;
    const int nb = ts[255];
    if (tid == 0) counts[b] = nb;
    for (int x = nb + tid; x < C_; x += 256) map[b * C_ + x] = 0;   // pads -> row 0
  }
}

// =====================================================================
// 256x256 GEMM (B-transposed), K=1024, BK=64, dbuf ring-2.
// R15 mechanism deepened: A0 serves P0+P1, B0/B1 resident all tile, so
// ALL {A0,B0,B1} reads (16, pinned groups 6/6/2/2) issue at P0 and A1's
// 8 (4/4) at P2; P1/P3 have no reads. Counted lgkm (FIFO DS, order
// pinned by sched_barrier): P0 lgkm(10)/(4); P1 lgkm(2)/(0);
// P2 lgkm(4)/(0). Same registers as R15 (WAR-on-reg pattern identical,
// with more intervening barriers).
// vmcnt ledger (8 glls/tile FIFO): stages P0:A0(t+1), P1:B0+B1(t+1),
// P2:A1(t+1), P3:none. Certs: P3(t-1) vmwait2 -> {A0,B0,B1}(t) before
// P0(t) reads; P1(t) vmwait6 -> A1(t) before P2(t) reads. Every cert
// lands 2-3 phases after issue. Prologue: stage A0,B0,B1,A1; vmwait2.
// Tail: no stages; P1 vmwait0 certifies A1(NT-1).
// LDS-overwrite audit: stage X(t+1) at Pk(t) is >=3 barriers after all
// waves' last reads of X(t-1) (each phase lgkm-drains before its end
// barrier). 8 barriers/tile unchanged (R6-proven skeleton).
//   MODE 0 (merged Q+KV): 1D grid 1152; tl<512 -> Q; else KV (gather
//     via map; skip-tail).  MODE 2 (SCORES): skip-tail via counts.
// LDS swizzle: phys_slot = logical ^ (row&7), both-sides (conflicts=0).
// =====================================================================
#define READ_A_K(DD, MQ, KK)                                              \
  _Pragma("unroll")                                                       \
  for (int f = 0; f < 4; ++f)                                             \
    a_[f][KK] = *(const bf16x8*)(sm + (((DD) + (MQ) * 8192 + A_pre + f * 1024) ^ ((KK) * 32)));

#define READ_B_K(DD, NQ, KK)                                              \
  _Pragma("unroll")                                                       \
  for (int n = 0; n < 2; ++n)                                             \
    b_[NQ][n][KK] = *(const bf16x8*)(sm + (((DD) + 16384 + (NQ) * 8192 + B_pre + n * 1024) ^ ((KK) * 32)));

#define MFMA_H(IO, JO, BQ, KK)                                            \
  __builtin_amdgcn_s_setprio(1);                                          \
  _Pragma("unroll")                                                       \
  for (int f = 0; f < 4; ++f)                                             \
    _Pragma("unroll")                                                     \
    for (int n = 0; n < 2; ++n)                                           \
      acc[(IO) + f][(JO) + n] = __builtin_amdgcn_mfma_f32_16x16x32_bf16(  \
          a_[f][KK], b_[BQ][n][KK], acc[(IO) + f][(JO) + n], 0, 0, 0);    \
  __builtin_amdgcn_s_setprio(0);

template <int MODE>
__global__ __launch_bounds__(512, 2) void k_gemm8(
    const u16* __restrict__ A, const u16* __restrict__ Bt,
    const float* __restrict__ bias, u16* __restrict__ C, u16* __restrict__ C2,
    const int* __restrict__ map, const int* __restrict__ counts, float scale) {
  extern __shared__ u16 sm[];            // 2 dbuf * 4 parts * 8192 u16 = 128 KiB
  constexpr int NT = 16;                 // 1024 / 64
  const int tid = threadIdx.x, lane = tid & 63, wave = tid >> 6;

  // XCD-aware bijective swizzle (nwg % 8 == 0 for both grids)
  const int gx = gridDim.x, gy = gridDim.y;
  const int nwg = gx * gy * gridDim.z;
  const int orig = blockIdx.x + gx * (blockIdx.y + gy * blockIdx.z);
  const int cpx = nwg >> 3;
  const int tl = (orig & 7) * cpx + (orig >> 3);

  const u16* Az; const u16* Bz;
  int batch = 0, mtile = 0, bx, by;
  bool isQ = false;
  if constexpr (MODE == 0) {
    if (tl < 512) {            // Q sub-job
      isQ = true;
      bx = tl & 3; by = tl >> 2;
      Az = A; Bz = Bt;
    } else {                   // KV sub-job
      const int i = tl - 512;
      bx = i & 7; by = i >> 3;
      batch = by / 5; mtile = by - batch * 5;
      if (mtile * 256 >= counts[batch]) return;    // dead compacted tile
      Az = A + (size_t)batch * S_ * D_;
      Bz = Bt + (size_t)D_ * D_;                   // Wt_kv (2048 rows)
    }
  } else {
    bx = tl % gx;
    const int rest = tl / gx;
    by = rest % gy;
    batch = rest / gy;
    if (bx * 256 >= counts[batch]) return;         // dead compacted col-tile
    Az = A + (size_t)batch * S_ * D_;
    Bz = Bt + (size_t)batch * C_ * D_;
  }
  const int wm_i = wave >> 2, wn_i = wave & 3;
  const int n0 = bx * 256;

  // ---- staging pointers (pre-swizzled global source; linear gll dest) ----
  const int grow = tid >> 3;                                   // 0..63
  const int gslot = ((tid & 7) ^ ((tid >> 3) & 7)) * 8;        // u16
  const u16 *pAa0, *pAb0, *pAa1, *pAb1;
  if (MODE == 0 && !isQ) {
    const int* mp = map + batch * C_ + mtile * 256;
    pAa0 = Az + (size_t)mp[grow] * D_ + gslot;
    pAb0 = Az + (size_t)mp[grow + 64] * D_ + gslot;
    pAa1 = Az + (size_t)mp[grow + 128] * D_ + gslot;
    pAb1 = Az + (size_t)mp[grow + 192] * D_ + gslot;
  } else {
    const int m0 = by * 256;
    pAa0 = Az + (size_t)(m0 + grow) * D_ + gslot;
    pAb0 = pAa0 + (size_t)64 * D_;
    pAa1 = pAa0 + (size_t)128 * D_;
    pAb1 = pAa0 + (size_t)192 * D_;
  }
  const u16* pBa0 = Bz + (size_t)(n0 + grow) * D_ + gslot;
  const u16* pBb0 = pBa0 + (size_t)64 * D_;
  const u16* pBa1 = pBa0 + (size_t)128 * D_;
  const u16* pBb1 = pBa0 + (size_t)192 * D_;

  // parts: 0=A0 1=A1 2=B0 3=B1 (LDS offset part*8192)
  auto stage_part = [&](int t, int part) {
    const u16* ga = (part == 0) ? pAa0 : (part == 1) ? pAa1 : (part == 2) ? pBa0 : pBa1;
    const u16* gb = (part == 0) ? pAb0 : (part == 1) ? pAb1 : (part == 2) ? pBb0 : pBb1;
    u16* l0 = sm + (t & 1) * 32768 + part * 8192 + wave * 512;
    gll16(ga + t * 64, l0);
    gll16(gb + t * 64, l0 + 4096);
  };

  // ---- read offsets (u16): phys_slot = logical ^ (row&7) ----
  const int r16 = lane & 15;
  const int s0k = (lane >> 4) ^ (lane & 7);
  const int A_pre = wm_i * 4096 + r16 * 64 + s0k * 8;   // + MQ*8192 + f*1024
  const int B_pre = wn_i * 2048 + r16 * 64 + s0k * 8;   // + 16384 + NQ*8192 + n*1024

  f32x4 acc[8][4] = {};
  bf16x8 a_[4][2], b_[2][2][2];

  // prologue: stage tile 0 in ledger order A0,B0,B1,A1; vmwait2 certifies {A0,B0,B1}
  stage_part(0, 0); stage_part(0, 2); stage_part(0, 3); stage_part(0, 1);
  vmwait2();
  barrier_pin();

#pragma unroll 1
  for (int t = 0; t < NT - 1; ++t) {
    const int DD = (t & 1) * 32768;
    // ---- P0: reads A0,B0,B1 (16, pinned 6/6/2/2); stage A0(t+1); no vmwait
    READ_A_K(DD, 0, 0) READ_B_K(DD, 0, 0)
    sbar();
    READ_A_K(DD, 0, 1) READ_B_K(DD, 0, 1)
    sbar();
    READ_B_K(DD, 1, 0)
    sbar();
    READ_B_K(DD, 1, 1)
    sbar();
    stage_part(t + 1, 0);
    barrier_pin();
    lgkm10(); MFMA_H(0, 0, 0, 0)
    lgkm4();  MFMA_H(0, 0, 0, 1)
    barrier_pin();
    // ---- P1: no reads; stage B0,B1(t+1); vmwait6 certifies A1(t)
    stage_part(t + 1, 2); stage_part(t + 1, 3);
    vmwait6(); barrier_pin();
    lgkm2();  MFMA_H(0, 2, 1, 0)
    lgkm0w(); MFMA_H(0, 2, 1, 1)
    barrier_pin();
    // ---- P2: reads A1 (8, pinned 4/4); stage A1(t+1); no vmwait
    READ_A_K(DD, 1, 0)
    sbar();
    READ_A_K(DD, 1, 1)
    sbar();
    stage_part(t + 1, 1);
    barrier_pin();
    lgkm4();  MFMA_H(4, 2, 1, 0)
    lgkm0w(); MFMA_H(4, 2, 1, 1)
    barrier_pin();
    // ---- P3: no reads/stages; vmwait2 certifies {A0,B0,B1}(t+1)
    vmwait2(); barrier_pin();
    MFMA_H(4, 0, 0, 0) MFMA_H(4, 0, 0, 1)
    barrier_pin();
  }
  {  // ---- tail tile (no stages); entry outstanding = [A1(NT-1)](2)
    const int DD = ((NT - 1) & 1) * 32768;
    READ_A_K(DD, 0, 0) READ_B_K(DD, 0, 0)
    sbar();
    READ_A_K(DD, 0, 1) READ_B_K(DD, 0, 1)
    sbar();
    READ_B_K(DD, 1, 0)
    sbar();
    READ_B_K(DD, 1, 1)
    sbar();
    barrier_pin();
    lgkm10(); MFMA_H(0, 0, 0, 0)
    lgkm4();  MFMA_H(0, 0, 0, 1)
    barrier_pin();
    vmwait0(); barrier_pin();
    lgkm2();  MFMA_H(0, 2, 1, 0)
    lgkm0w(); MFMA_H(0, 2, 1, 1)
    barrier_pin();
    READ_A_K(DD, 1, 0)
    sbar();
    READ_A_K(DD, 1, 1)
    sbar();
    barrier_pin();
    lgkm4();  MFMA_H(4, 2, 1, 0)
    lgkm0w(); MFMA_H(4, 2, 1, 1)
    barrier_pin();
    MFMA_H(4, 0, 0, 0) MFMA_H(4, 0, 0, 1)
  }

  // epilogue: C/D layout col = lane&15, row = (lane>>4)*4 + r
#pragma unroll
  for (int i = 0; i < 8; ++i) {
    const int MQ = i >> 2, f = i & 3;
    const int lrow = MQ * 128 + wm_i * 64 + f * 16 + ((lane >> 4) << 2);
#pragma unroll
    for (int j = 0; j < 4; ++j) {
      const int NQ = j >> 1, n = j & 1;
      const int col = n0 + NQ * 128 + wn_i * 32 + n * 16 + (lane & 15);
      if constexpr (MODE == 0) {
        if (isQ) {
          const float badd = bias[col];
          u16* cp = C + (size_t)(by * 256 + lrow) * 1024 + col;
#pragma unroll
          for (int r = 0; r < 4; ++r) cp[(size_t)r * 1024] = f2b(acc[i][j][r] + badd);
        } else {
          const float badd = bias[1024 + col];
          u16* cp = C2 + (size_t)(col >> 10) * ((size_t)16 * C_ * 1024)
                      + ((size_t)batch * C_ + mtile * 256 + lrow) * 1024 + (col & 1023);
#pragma unroll
          for (int r = 0; r < 4; ++r) cp[(size_t)r * 1024] = f2b(acc[i][j][r] + badd);
        }
      } else {
        u16* cp = C + ((size_t)batch * 2048 + by * 256 + lrow) * C_ + col;
#pragma unroll
        for (int r = 0; r < 4; ++r) cp[(size_t)r * C_] = f2b(acc[i][j][r] * scale);
      }
    }
  }
}

// ---------------- softmax rows + column-sum partials over compacted cols
// grid (32, 16): block = 64 q-rows of batch b; writes cpart[b*32+bi][0..C_)
__global__ __launch_bounds__(256) void k_softmax_colsum(
    const u16* __restrict__ Sc, const int* __restrict__ counts,
    float* __restrict__ cpart) {
  __shared__ float colsum[C_];
  const int b = blockIdx.y, bi = blockIdx.x;
  const int tid = threadIdx.x, lane = tid & 63, wave = tid >> 6;
  for (int k = tid; k < C_; k += 256) colsum[k] = 0.0f;
  __syncthreads();

  const int nb = counts[b];
  const u16* base = Sc + ((size_t)b * 2048 + bi * 64 + wave * 16) * C_;
  const int c16 = lane * 16;          // cols [c16, c16+16)
  const int c4 = 1024 + lane * 4;     // cols [c4, c4+4)
  float csum[20];
#pragma unroll
  for (int i = 0; i < 20; i++) csum[i] = 0.0f;

  for (int rr = 0; rr < 16; rr++) {
    const u16* srow = base + (size_t)rr * C_;
    usx8 x0 = *(const usx8*)(srow + c16);
    usx8 x1 = *(const usx8*)(srow + c16 + 8);
    usx4 x2 = *(const usx4*)(srow + c4);
    float s[20];
    float m = -1e30f;
#pragma unroll
    for (int e = 0; e < 8; e++) {
      s[e] = (c16 + e < nb) ? b2f(x0[e]) : -1e30f;
      s[8 + e] = (c16 + 8 + e < nb) ? b2f(x1[e]) : -1e30f;
      m = fmaxf(m, fmaxf(s[e], s[8 + e]));
    }
#pragma unroll
    for (int e = 0; e < 4; e++) {
      s[16 + e] = (c4 + e < nb) ? b2f(x2[e]) : -1e30f;
      m = fmaxf(m, s[16 + e]);
    }
#pragma unroll
    for (int o = 1; o < 64; o <<= 1) m = fmaxf(m, __shfl_xor(m, o));
    float sum = 0.f;
#pragma unroll
    for (int i = 0; i < 20; i++) { s[i] = __expf(s[i] - m); sum += s[i]; }
#pragma unroll
    for (int o = 1; o < 64; o <<= 1) sum += __shfl_xor(sum, o);
    const float inv = 1.0f / (sum * (float)S_);
#pragma unroll
    for (int i = 0; i < 20; i++) csum[i] += s[i] * inv;
  }
#pragma unroll
  for (int i = 0; i < 16; i++) {
    const int e = (i + lane) & 15;
    atomicAdd(&colsum[c16 + e], csum[e]);
  }
#pragma unroll
  for (int i = 0; i < 4; i++) {
    const int e = (i + lane) & 3;
    atomicAdd(&colsum[c4 + e], csum[16 + e]);
  }
  __syncthreads();
  float* dst = cpart + ((size_t)b * 32 + bi) * C_;
  for (int k = tid; k < C_; k += 256) dst[k] = colsum[k];
}

// ---------------- pooled[b,d] += sum_{kc in slice} c[b,kc] * V_c[b,kc,d]
__global__ __launch_bounds__(256) void k_cv(const float* __restrict__ cpart,
                                            const u16* __restrict__ Vc,
                                            float* __restrict__ pooled) {
  __shared__ float cl[128];
  const int b = blockIdx.y;
  const int k0 = blockIdx.x * 128;
  const int tid = threadIdx.x;
  if (tid < 128) {
    float s = 0.f;
    const float* p = cpart + (size_t)b * 32 * C_ + k0 + tid;
#pragma unroll 4
    for (int q = 0; q < 32; q++) s += p[(size_t)q * C_];
    cl[tid] = s;
  }
  __syncthreads();
  f32x4 acc = {};
  const u16* vb = Vc + ((size_t)b * C_ + k0) * 1024 + tid * 4;
  for (int k = 0; k < 128; k++) {
    const float w = cl[k];
    usx4 v = *(const usx4*)(vb + (size_t)k * 1024);
    acc[0] += w * b2f(v[0]);
    acc[1] += w * b2f(v[1]);
    acc[2] += w * b2f(v[2]);
    acc[3] += w * b2f(v[3]);
  }
#pragma unroll
  for (int q = 0; q < 4; q++) atomicAdd(&pooled[b * D_ + tid * 4 + q], acc[q]);
}

// ---------------- hpre = pooled @ W1 (atomic K-split, grid (16,16))
__global__ __launch_bounds__(256) void k_mlp1(const float* __restrict__ pooled,
                                              const float* __restrict__ W1,
                                              float* __restrict__ hpre) {
  __shared__ float ps[16][64];
  const int tid = threadIdx.x;
  const int j = blockIdx.x * 256 + tid;
  const int i0 = blockIdx.y * 64;
  for (int x = tid; x < 16 * 64; x += 256) {
    const int bb = x >> 6, ii = x & 63;
    ps[bb][ii] = pooled[bb * D_ + i0 + ii];
  }
  __syncthreads();
  float acc[16] = {};
  for (int i = 0; i < 64; i++) {
    const float w = W1[(size_t)(i0 + i) * (4 * D_) + j];
#pragma unroll
    for (int bb = 0; bb < 16; bb++) acc[bb] += ps[bb][i] * w;
  }
#pragma unroll
  for (int bb = 0; bb < 16; bb++) atomicAdd(&hpre[bb * (4 * D_) + j], acc[bb]);
}

// ---------------- outpre = relu(hpre + b1) @ W2 (atomic K-split, grid (4,64))
__global__ __launch_bounds__(256) void k_mlp2(const float* __restrict__ hpre,
                                              const float* __restrict__ b1,
                                              const float* __restrict__ W2,
                                              float* __restrict__ outpre) {
  __shared__ float hs[16][64];
  const int tid = threadIdx.x;
  const int n = blockIdx.x * 256 + tid;
  const int i0 = blockIdx.y * 64;
  for (int x = tid; x < 16 * 64; x += 256) {
    const int bb = x >> 6, ii = x & 63;
    hs[bb][ii] = fmaxf(hpre[bb * (4 * D_) + i0 + ii] + b1[i0 + ii], 0.0f);
  }
  __syncthreads();
  float acc[16] = {};
  for (int i = 0; i < 64; i++) {
    const float w = W2[(size_t)(i0 + i) * D_ + n];
#pragma unroll
    for (int bb = 0; bb < 16; bb++) acc[bb] += hs[bb][i] * w;
  }
#pragma unroll
  for (int bb = 0; bb < 16; bb++) atomicAdd(&outpre[bb * D_ + n], acc[bb]);
}

// ---------------- out = tanh(outpre + b2)
__global__ void k_finish(const float* __restrict__ outpre, const float* __restrict__ b2,
                         float* __restrict__ out) {
  const int x = blockIdx.x * 256 + threadIdx.x;
  out[x] = tanhf(outpre[x] + b2[x & (D_ - 1)]);
}

extern "C" void kernel_launch(void* const* d_in, const int* in_sizes, int n_in,
                              void* d_out, int out_size, void* d_ws, size_t ws_size,
                              hipStream_t stream) {
  const float* X  = (const float*)d_in[0];
  const int* mask = (const int*)d_in[1];
  const float* Wq = (const float*)d_in[2];
  const float* bq = (const float*)d_in[3];
  const float* Wk = (const float*)d_in[4];
  const float* bk = (const float*)d_in[5];
  const float* Wv = (const float*)d_in[6];
  const float* bv = (const float*)d_in[7];
  const float* W1 = (const float*)d_in[8];
  const float* b1 = (const float*)d_in[9];
  const float* W2 = (const float*)d_in[10];
  const float* b2 = (const float*)d_in[11];
  float* out = (float*)d_out;

  char* ws = (char*)d_ws;
  size_t off = 0;
  auto alloc = [&](size_t bytes) -> void* {
    void* p = ws + off;
    off += (bytes + 255) & ~(size_t)255;
    return p;
  };
  u16* Qb  = (u16*)alloc(BSD * sizeof(u16));                          // 64 MB
  u16* KVc = (u16*)alloc((size_t)2 * 16 * C_ * D_ * sizeof(u16));     // 80 MB (K_c | V_c)
  u16* Kc  = KVc;
  u16* Vc  = KVc + (size_t)16 * C_ * D_;
  u16* ScX = (u16*)alloc((size_t)16 * 2048 * C_ * sizeof(u16));       // 80 MB
  u16* Xb  = ScX;   // X-bf16 aliases Sc: consumed by Q/KV GEMMs before Sc written
  u16* Sc  = ScX;
  u16* Wt  = (u16*)alloc((size_t)3 * D_ * D_ * sizeof(u16));          // 6 MB
  float* biasQKV = (float*)alloc(3 * D_ * sizeof(float));
  int* map    = (int*)alloc((size_t)16 * C_ * sizeof(int));           // 80 KB
  int* counts = (int*)alloc(16 * sizeof(int));
  float* cpart  = (float*)alloc((size_t)32 * 16 * C_ * sizeof(float)); // 2.6 MB
  float* pooled = (float*)alloc((size_t)B_ * D_ * sizeof(float));
  float* hpre   = (float*)alloc((size_t)B_ * 4 * D_ * sizeof(float));
  float* outpre = (float*)alloc((size_t)B_ * D_ * sizeof(float));
  (void)ws_size; (void)in_sizes; (void)n_in; (void)out_size;

  const size_t zero_bytes = (size_t)B_ * D_ * 4 + (size_t)B_ * 4 * D_ * 4 +
                            (size_t)B_ * D_ * 4;
  hipMemsetAsync(pooled, 0, zero_bytes, stream);

  // fused prep: cvt_x (16384) + W transpose (3072) + bias (1) + mask scan (16)
  k_prep<<<16384 + 3089, 256, 0, stream>>>(X, Xb, Wq, Wk, Wv, bq, bk, bv,
                                           mask, Wt, biasQKV, map, counts);

  // merged Q + KV GEMM: 512 + 640 = 1152 blocks
  k_gemm8<0><<<dim3(1152, 1, 1), 512, 131072, stream>>>(
      Xb, Wt, biasQKV, Qb, KVc, map, counts, 1.0f);

  // Sc[b,q,kc] = (Q[b,q,:] . K_c[b,kc,:]) / 32  (skip-tail; overwrites Xb alias)
  k_gemm8<2><<<dim3(C_ / 256, 8, 16), 512, 131072, stream>>>(
      Qb, Kc, nullptr, Sc, nullptr, nullptr, counts, 0.03125f);

  k_softmax_colsum<<<dim3(32, B_), 256, 0, stream>>>(Sc, counts, cpart);
  k_cv<<<dim3(C_ / 128, B_), 256, 0, stream>>>(cpart, Vc, pooled);
  k_mlp1<<<dim3(16, 16), 256, 0, stream>>>(pooled, W1, hpre);
  k_mlp2<<<dim3(4, 64), 256, 0, stream>>>(hpre, b1, W2, outpre);
  k_finish<<<64, 256, 0, stream>>>(outpre, b2, out);
}

// Round 17
// 390.360 us; speedup vs baseline: 1.0219x; 1.0219x over previous
//
#include <hip/hip_runtime.h>
#include <hip/hip_bf16.h>

constexpr int B_ = 16;
constexpr int S_ = 2048;
constexpr int D_ = 1024;
constexpr int C_ = 1280;                              // compacted K capacity (5*256)
constexpr long long BSD = (long long)B_ * S_ * D_;   // 33,554,432

typedef unsigned short u16;
typedef __bf16 bf16x8 __attribute__((ext_vector_type(8)));
typedef float    f32x4 __attribute__((ext_vector_type(4)));
typedef unsigned short usx8 __attribute__((ext_vector_type(8)));
typedef unsigned short usx4 __attribute__((ext_vector_type(4)));

__device__ inline u16 f2b(float f) {            // f32 -> bf16 RNE
  unsigned u = __float_as_uint(f);
  u = (u + 0x7fffu + ((u >> 16) & 1u)) >> 16;
  return (u16)u;
}
__device__ inline float b2f(u16 v) { return __uint_as_float(((unsigned)v) << 16); }

__device__ __forceinline__ void gll16(const void* g, void* l) {
  __builtin_amdgcn_global_load_lds(
      (const __attribute__((address_space(1))) void*)g,
      (__attribute__((address_space(3))) void*)l, 16, 0, 0);
}

__device__ __forceinline__ void vmwait4() {
  asm volatile("s_waitcnt vmcnt(4)" ::: "memory");
  __builtin_amdgcn_sched_barrier(0);
}
__device__ __forceinline__ void vmwait2() {
  asm volatile("s_waitcnt vmcnt(2)" ::: "memory");
  __builtin_amdgcn_sched_barrier(0);
}
__device__ __forceinline__ void vmwait0() {
  asm volatile("s_waitcnt vmcnt(0)" ::: "memory");
  __builtin_amdgcn_sched_barrier(0);
}
__device__ __forceinline__ void lgkm6() {
  asm volatile("s_waitcnt lgkmcnt(6)" ::: "memory");
  __builtin_amdgcn_sched_barrier(0);
}
__device__ __forceinline__ void lgkm4() {
  asm volatile("s_waitcnt lgkmcnt(4)" ::: "memory");
  __builtin_amdgcn_sched_barrier(0);
}
__device__ __forceinline__ void lgkm2() {
  asm volatile("s_waitcnt lgkmcnt(2)" ::: "memory");
  __builtin_amdgcn_sched_barrier(0);
}
__device__ __forceinline__ void lgkm0w() {
  asm volatile("s_waitcnt lgkmcnt(0)" ::: "memory");
  __builtin_amdgcn_sched_barrier(0);
}
__device__ __forceinline__ void sbar() { __builtin_amdgcn_sched_barrier(0); }
__device__ __forceinline__ void barrier_pin() {
  __builtin_amdgcn_sched_barrier(0);
  __builtin_amdgcn_s_barrier();
  __builtin_amdgcn_sched_barrier(0);
}

// ---------------- fused prep: X cvt (16384), W transpose+cvt (3072),
// bias pack (1), per-batch mask compaction scan (16) ----------------
__global__ __launch_bounds__(256) void k_prep(
    const float* __restrict__ X, u16* __restrict__ Xb,
    const float* __restrict__ Wq, const float* __restrict__ Wk, const float* __restrict__ Wv,
    const float* __restrict__ bq, const float* __restrict__ bk, const float* __restrict__ bv,
    const int* __restrict__ mask, u16* __restrict__ Wt,
    float* __restrict__ biasQKV, int* __restrict__ map, int* __restrict__ counts) {
  __shared__ float tile[32][33];
  __shared__ int ts[256];
  const int bid = blockIdx.x;
  const int tid = threadIdx.x;
  if (bid < 16384) {
    size_t i = ((size_t)bid * 256 + tid) * 8;
    f32x4 a = *(const f32x4*)(X + i);
    f32x4 b = *(const f32x4*)(X + i + 4);
    usx8 o;
    o[0] = f2b(a[0]); o[1] = f2b(a[1]); o[2] = f2b(a[2]); o[3] = f2b(a[3]);
    o[4] = f2b(b[0]); o[5] = f2b(b[1]); o[6] = f2b(b[2]); o[7] = f2b(b[3]);
    *(usx8*)(Xb + i) = o;
  } else if (bid < 16384 + 3072) {
    const int wb = bid - 16384;
    const int z = wb >> 10, t = wb & 1023;
    const float* W = (z == 0) ? Wq : (z == 1 ? Wk : Wv);
    u16* dst = Wt + (size_t)z * D_ * D_;
    const int n0 = (t & 31) * 32, k0 = (t >> 5) * 32;
    const int tx = tid & 31, ty = tid >> 5;
    for (int r = ty; r < 32; r += 8)
      tile[r][tx] = W[(size_t)(k0 + r) * D_ + n0 + tx];
    __syncthreads();
    for (int r = ty; r < 32; r += 8)
      dst[(size_t)(n0 + r) * D_ + k0 + tx] = f2b(tile[tx][r]);
  } else if (bid == 16384 + 3072) {
    for (int x = tid; x < 3072; x += 256)
      biasQKV[x] = (x < 1024) ? bq[x] : (x < 2048 ? bk[x - 1024] : bv[x - 2048]);
  } else {
    const int b = bid - (16384 + 3073);
    const int* mrow = mask + b * S_;
    int lv[8]; int s = 0;
#pragma unroll
    for (int j = 0; j < 8; ++j) { lv[j] = (mrow[tid * 8 + j] != 0) ? 1 : 0; s += lv[j]; }
    ts[tid] = s;
    __syncthreads();
    for (int off = 1; off < 256; off <<= 1) {
      int v = (tid >= off) ? ts[tid - off] : 0;
      __syncthreads();
      ts[tid] += v;
      __syncthreads();
    }
    int pos = ts[tid] - s;                        // exclusive prefix
#pragma unroll
    for (int j = 0; j < 8; ++j) if (lv[j]) map[b * C_ + (pos++)] = tid * 8 + j;
    const int nb = ts[255];
    if (tid == 0) counts[b] = nb;
    for (int x = nb + tid; x < C_; x += 256) map[b * C_ + x] = 0;   // pads -> row 0
  }
}

// =====================================================================
// 256x256 GEMM (B-transposed), K=1024, BK=64, dbuf ring-2 — EXACT R15
// (best proven: 395 us total, merged ~183 us). R6 barrier skeleton
// (8 barriers/tile) + R6 vmcnt ledger + kk-split counted lgkm with
// emission order pinned by sched_barrier between kk groups:
//   per phase: kk0 reads | sbar | kk1 reads | sbar | stage | vmwait |
//   barrier | lgkm(#outstanding kk1) MFMA-half0 | lgkm(0) MFMA-half1 |
//   barrier.
// vmcnt ledger: stages (t+1): P0:A0 P1:B0 P2:B1 P3:A1; vmwait4 certs:
//   P3(t-1)->P0(t) reads, P0->B1, P1->A1, P2 none. Tail: 2/0/-/-.
//   MODE 0 (merged Q+KV): 1D grid 1152; tl<512 -> Q; else KV (gather
//     via map; skip-tail).  MODE 2 (SCORES): skip-tail via counts.
// LDS swizzle: phys_slot = logical ^ (row&7), both-sides (conflicts=0).
// =====================================================================
#define READ_A_K(DD, MQ, KK)                                              \
  _Pragma("unroll")                                                       \
  for (int f = 0; f < 4; ++f)                                             \
    a_[f][KK] = *(const bf16x8*)(sm + (((DD) + (MQ) * 8192 + A_pre + f * 1024) ^ ((KK) * 32)));

#define READ_B_K(DD, NQ, KK)                                              \
  _Pragma("unroll")                                                       \
  for (int n = 0; n < 2; ++n)                                             \
    b_[NQ][n][KK] = *(const bf16x8*)(sm + (((DD) + 16384 + (NQ) * 8192 + B_pre + n * 1024) ^ ((KK) * 32)));

#define MFMA_H(IO, JO, BQ, KK)                                            \
  __builtin_amdgcn_s_setprio(1);                                          \
  _Pragma("unroll")                                                       \
  for (int f = 0; f < 4; ++f)                                             \
    _Pragma("unroll")                                                     \
    for (int n = 0; n < 2; ++n)                                           \
      acc[(IO) + f][(JO) + n] = __builtin_amdgcn_mfma_f32_16x16x32_bf16(  \
          a_[f][KK], b_[BQ][n][KK], acc[(IO) + f][(JO) + n], 0, 0, 0);    \
  __builtin_amdgcn_s_setprio(0);

template <int MODE>
__global__ __launch_bounds__(512, 2) void k_gemm8(
    const u16* __restrict__ A, const u16* __restrict__ Bt,
    const float* __restrict__ bias, u16* __restrict__ C, u16* __restrict__ C2,
    const int* __restrict__ map, const int* __restrict__ counts, float scale) {
  extern __shared__ u16 sm[];            // 2 dbuf * 4 parts * 8192 u16 = 128 KiB
  constexpr int NT = 16;                 // 1024 / 64
  const int tid = threadIdx.x, lane = tid & 63, wave = tid >> 6;

  // XCD-aware bijective swizzle (nwg % 8 == 0 for both grids)
  const int gx = gridDim.x, gy = gridDim.y;
  const int nwg = gx * gy * gridDim.z;
  const int orig = blockIdx.x + gx * (blockIdx.y + gy * blockIdx.z);
  const int cpx = nwg >> 3;
  const int tl = (orig & 7) * cpx + (orig >> 3);

  const u16* Az; const u16* Bz;
  int batch = 0, mtile = 0, bx, by;
  bool isQ = false;
  if constexpr (MODE == 0) {
    if (tl < 512) {            // Q sub-job
      isQ = true;
      bx = tl & 3; by = tl >> 2;
      Az = A; Bz = Bt;
    } else {                   // KV sub-job
      const int i = tl - 512;
      bx = i & 7; by = i >> 3;
      batch = by / 5; mtile = by - batch * 5;
      if (mtile * 256 >= counts[batch]) return;    // dead compacted tile
      Az = A + (size_t)batch * S_ * D_;
      Bz = Bt + (size_t)D_ * D_;                   // Wt_kv (2048 rows)
    }
  } else {
    bx = tl % gx;
    const int rest = tl / gx;
    by = rest % gy;
    batch = rest / gy;
    if (bx * 256 >= counts[batch]) return;         // dead compacted col-tile
    Az = A + (size_t)batch * S_ * D_;
    Bz = Bt + (size_t)batch * C_ * D_;
  }
  const int wm_i = wave >> 2, wn_i = wave & 3;
  const int n0 = bx * 256;

  // ---- staging pointers (pre-swizzled global source; linear gll dest) ----
  const int grow = tid >> 3;                                   // 0..63
  const int gslot = ((tid & 7) ^ ((tid >> 3) & 7)) * 8;        // u16
  const u16 *pAa0, *pAb0, *pAa1, *pAb1;
  if (MODE == 0 && !isQ) {
    const int* mp = map + batch * C_ + mtile * 256;
    pAa0 = Az + (size_t)mp[grow] * D_ + gslot;
    pAb0 = Az + (size_t)mp[grow + 64] * D_ + gslot;
    pAa1 = Az + (size_t)mp[grow + 128] * D_ + gslot;
    pAb1 = Az + (size_t)mp[grow + 192] * D_ + gslot;
  } else {
    const int m0 = by * 256;
    pAa0 = Az + (size_t)(m0 + grow) * D_ + gslot;
    pAb0 = pAa0 + (size_t)64 * D_;
    pAa1 = pAa0 + (size_t)128 * D_;
    pAb1 = pAa0 + (size_t)192 * D_;
  }
  const u16* pBa0 = Bz + (size_t)(n0 + grow) * D_ + gslot;
  const u16* pBb0 = pBa0 + (size_t)64 * D_;
  const u16* pBa1 = pBa0 + (size_t)128 * D_;
  const u16* pBb1 = pBa0 + (size_t)192 * D_;

  // parts: 0=A0 1=A1 2=B0 3=B1 (LDS offset part*8192)
  auto stage_part = [&](int t, int part) {
    const u16* ga = (part == 0) ? pAa0 : (part == 1) ? pAa1 : (part == 2) ? pBa0 : pBa1;
    const u16* gb = (part == 0) ? pAb0 : (part == 1) ? pAb1 : (part == 2) ? pBb0 : pBb1;
    u16* l0 = sm + (t & 1) * 32768 + part * 8192 + wave * 512;
    gll16(ga + t * 64, l0);
    gll16(gb + t * 64, l0 + 4096);
  };

  // ---- read offsets (u16): phys_slot = logical ^ (row&7) ----
  const int r16 = lane & 15;
  const int s0k = (lane >> 4) ^ (lane & 7);
  const int A_pre = wm_i * 4096 + r16 * 64 + s0k * 8;   // + MQ*8192 + f*1024
  const int B_pre = wn_i * 2048 + r16 * 64 + s0k * 8;   // + 16384 + NQ*8192 + n*1024

  f32x4 acc[8][4] = {};
  bf16x8 a_[4][2], b_[2][2][2];

  // prologue: stage tile 0 in ledger order A0,B0,B1,A1; certify {A0,B0}
  stage_part(0, 0); stage_part(0, 2); stage_part(0, 3); stage_part(0, 1);
  vmwait4();
  barrier_pin();

#pragma unroll 1
  for (int t = 0; t < NT - 1; ++t) {
    const int DD = (t & 1) * 32768;
    // ---- P0: reads A0,B0 (kk0 pinned first); stage A0(t+1); certify B1(t)
    READ_A_K(DD, 0, 0) READ_B_K(DD, 0, 0)
    sbar();
    READ_A_K(DD, 0, 1) READ_B_K(DD, 0, 1)
    sbar();
    stage_part(t + 1, 0);
    vmwait4(); barrier_pin();
    lgkm6();  MFMA_H(0, 0, 0, 0)
    lgkm0w(); MFMA_H(0, 0, 0, 1)
    barrier_pin();
    // ---- P1: reads B1 (kk-split); stage B0(t+1); certify A1(t)
    READ_B_K(DD, 1, 0)
    sbar();
    READ_B_K(DD, 1, 1)
    sbar();
    stage_part(t + 1, 2);
    vmwait4(); barrier_pin();
    lgkm2();  MFMA_H(0, 2, 1, 0)
    lgkm0w(); MFMA_H(0, 2, 1, 1)
    barrier_pin();
    // ---- P2: reads A1 (kk-split); stage B1(t+1); no vm wait
    READ_A_K(DD, 1, 0)
    sbar();
    READ_A_K(DD, 1, 1)
    sbar();
    stage_part(t + 1, 3);
    barrier_pin();
    lgkm4();  MFMA_H(4, 2, 1, 0)
    lgkm0w(); MFMA_H(4, 2, 1, 1)
    barrier_pin();
    // ---- P3: no reads; stage A1(t+1); certify {A0,B0}(t+1)
    stage_part(t + 1, 1);
    vmwait4(); barrier_pin();
    MFMA_H(4, 0, 0, 0) MFMA_H(4, 0, 0, 1)
    barrier_pin();
  }
  {  // ---- tail tile (no stages)
    const int DD = ((NT - 1) & 1) * 32768;
    READ_A_K(DD, 0, 0) READ_B_K(DD, 0, 0)
    sbar();
    READ_A_K(DD, 0, 1) READ_B_K(DD, 0, 1)
    sbar();
    vmwait2(); barrier_pin();
    lgkm6();  MFMA_H(0, 0, 0, 0)
    lgkm0w(); MFMA_H(0, 0, 0, 1)
    barrier_pin();
    READ_B_K(DD, 1, 0)
    sbar();
    READ_B_K(DD, 1, 1)
    sbar();
    vmwait0(); barrier_pin();
    lgkm2();  MFMA_H(0, 2, 1, 0)
    lgkm0w(); MFMA_H(0, 2, 1, 1)
    barrier_pin();
    READ_A_K(DD, 1, 0)
    sbar();
    READ_A_K(DD, 1, 1)
    sbar();
    barrier_pin();
    lgkm4();  MFMA_H(4, 2, 1, 0)
    lgkm0w(); MFMA_H(4, 2, 1, 1)
    barrier_pin();
    MFMA_H(4, 0, 0, 0) MFMA_H(4, 0, 0, 1)
  }

  // epilogue: C/D layout col = lane&15, row = (lane>>4)*4 + r
#pragma unroll
  for (int i = 0; i < 8; ++i) {
    const int MQ = i >> 2, f = i & 3;
    const int lrow = MQ * 128 + wm_i * 64 + f * 16 + ((lane >> 4) << 2);
#pragma unroll
    for (int j = 0; j < 4; ++j) {
      const int NQ = j >> 1, n = j & 1;
      const int col = n0 + NQ * 128 + wn_i * 32 + n * 16 + (lane & 15);
      if constexpr (MODE == 0) {
        if (isQ) {
          const float badd = bias[col];
          u16* cp = C + (size_t)(by * 256 + lrow) * 1024 + col;
#pragma unroll
          for (int r = 0; r < 4; ++r) cp[(size_t)r * 1024] = f2b(acc[i][j][r] + badd);
        } else {
          const float badd = bias[1024 + col];
          u16* cp = C2 + (size_t)(col >> 10) * ((size_t)16 * C_ * 1024)
                      + ((size_t)batch * C_ + mtile * 256 + lrow) * 1024 + (col & 1023);
#pragma unroll
          for (int r = 0; r < 4; ++r) cp[(size_t)r * 1024] = f2b(acc[i][j][r] + badd);
        }
      } else {
        u16* cp = C + ((size_t)batch * 2048 + by * 256 + lrow) * C_ + col;
#pragma unroll
        for (int r = 0; r < 4; ++r) cp[(size_t)r * C_] = f2b(acc[i][j][r] * scale);
      }
    }
  }
}

// ---------------- softmax rows + column-sum partials over compacted cols
// grid (32, 16): block = 64 q-rows of batch b; writes cpart[b*32+bi][0..C_)
// Fast path: lanes whose full 16/4-col range lies below nb skip the
// per-element bound checks (identical numerics; boundary lanes unchanged).
__global__ __launch_bounds__(256) void k_softmax_colsum(
    const u16* __restrict__ Sc, const int* __restrict__ counts,
    float* __restrict__ cpart) {
  __shared__ float colsum[C_];
  const int b = blockIdx.y, bi = blockIdx.x;
  const int tid = threadIdx.x, lane = tid & 63, wave = tid >> 6;
  for (int k = tid; k < C_; k += 256) colsum[k] = 0.0f;
  __syncthreads();

  const int nb = counts[b];
  const u16* base = Sc + ((size_t)b * 2048 + bi * 64 + wave * 16) * C_;
  const int c16 = lane * 16;          // cols [c16, c16+16)
  const int c4 = 1024 + lane * 4;     // cols [c4, c4+4)
  const bool full16 = (c16 + 16 <= nb);
  const bool full4  = (c4 + 4 <= nb);
  float csum[20];
#pragma unroll
  for (int i = 0; i < 20; i++) csum[i] = 0.0f;

  for (int rr = 0; rr < 16; rr++) {
    const u16* srow = base + (size_t)rr * C_;
    usx8 x0 = *(const usx8*)(srow + c16);
    usx8 x1 = *(const usx8*)(srow + c16 + 8);
    usx4 x2 = *(const usx4*)(srow + c4);
    float s[20];
    float m = -1e30f;
    if (full16) {
#pragma unroll
      for (int e = 0; e < 8; e++) {
        s[e] = b2f(x0[e]);
        s[8 + e] = b2f(x1[e]);
        m = fmaxf(m, fmaxf(s[e], s[8 + e]));
      }
    } else {
#pragma unroll
      for (int e = 0; e < 8; e++) {
        s[e] = (c16 + e < nb) ? b2f(x0[e]) : -1e30f;
        s[8 + e] = (c16 + 8 + e < nb) ? b2f(x1[e]) : -1e30f;
        m = fmaxf(m, fmaxf(s[e], s[8 + e]));
      }
    }
    if (full4) {
#pragma unroll
      for (int e = 0; e < 4; e++) {
        s[16 + e] = b2f(x2[e]);
        m = fmaxf(m, s[16 + e]);
      }
    } else {
#pragma unroll
      for (int e = 0; e < 4; e++) {
        s[16 + e] = (c4 + e < nb) ? b2f(x2[e]) : -1e30f;
        m = fmaxf(m, s[16 + e]);
      }
    }
#pragma unroll
    for (int o = 1; o < 64; o <<= 1) m = fmaxf(m, __shfl_xor(m, o));
    float sum = 0.f;
#pragma unroll
    for (int i = 0; i < 20; i++) { s[i] = __expf(s[i] - m); sum += s[i]; }
#pragma unroll
    for (int o = 1; o < 64; o <<= 1) sum += __shfl_xor(sum, o);
    const float inv = 1.0f / (sum * (float)S_);
#pragma unroll
    for (int i = 0; i < 20; i++) csum[i] += s[i] * inv;
  }
#pragma unroll
  for (int i = 0; i < 16; i++) {
    const int e = (i + lane) & 15;
    atomicAdd(&colsum[c16 + e], csum[e]);
  }
#pragma unroll
  for (int i = 0; i < 4; i++) {
    const int e = (i + lane) & 3;
    atomicAdd(&colsum[c4 + e], csum[16 + e]);
  }
  __syncthreads();
  float* dst = cpart + ((size_t)b * 32 + bi) * C_;
  for (int k = tid; k < C_; k += 256) dst[k] = colsum[k];
}

// ---------------- pooled[b,d] += sum_{kc in slice} c[b,kc] * V_c[b,kc,d]
__global__ __launch_bounds__(256) void k_cv(const float* __restrict__ cpart,
                                            const u16* __restrict__ Vc,
                                            float* __restrict__ pooled) {
  __shared__ float cl[128];
  const int b = blockIdx.y;
  const int k0 = blockIdx.x * 128;
  const int tid = threadIdx.x;
  if (tid < 128) {
    float s = 0.f;
    const float* p = cpart + (size_t)b * 32 * C_ + k0 + tid;
#pragma unroll 4
    for (int q = 0; q < 32; q++) s += p[(size_t)q * C_];
    cl[tid] = s;
  }
  __syncthreads();
  f32x4 acc = {};
  const u16* vb = Vc + ((size_t)b * C_ + k0) * 1024 + tid * 4;
  for (int k = 0; k < 128; k++) {
    const float w = cl[k];
    usx4 v = *(const usx4*)(vb + (size_t)k * 1024);
    acc[0] += w * b2f(v[0]);
    acc[1] += w * b2f(v[1]);
    acc[2] += w * b2f(v[2]);
    acc[3] += w * b2f(v[3]);
  }
#pragma unroll
  for (int q = 0; q < 4; q++) atomicAdd(&pooled[b * D_ + tid * 4 + q], acc[q]);
}

// ---------------- hpre = pooled @ W1 (atomic K-split, grid (16,16))
__global__ __launch_bounds__(256) void k_mlp1(const float* __restrict__ pooled,
                                              const float* __restrict__ W1,
                                              float* __restrict__ hpre) {
  __shared__ float ps[16][64];
  const int tid = threadIdx.x;
  const int j = blockIdx.x * 256 + tid;
  const int i0 = blockIdx.y * 64;
  for (int x = tid; x < 16 * 64; x += 256) {
    const int bb = x >> 6, ii = x & 63;
    ps[bb][ii] = pooled[bb * D_ + i0 + ii];
  }
  __syncthreads();
  float acc[16] = {};
  for (int i = 0; i < 64; i++) {
    const float w = W1[(size_t)(i0 + i) * (4 * D_) + j];
#pragma unroll
    for (int bb = 0; bb < 16; bb++) acc[bb] += ps[bb][i] * w;
  }
#pragma unroll
  for (int bb = 0; bb < 16; bb++) atomicAdd(&hpre[bb * (4 * D_) + j], acc[bb]);
}

// ---------------- outpre = relu(hpre + b1) @ W2 (atomic K-split, grid (4,64))
__global__ __launch_bounds__(256) void k_mlp2(const float* __restrict__ hpre,
                                              const float* __restrict__ b1,
                                              const float* __restrict__ W2,
                                              float* __restrict__ outpre) {
  __shared__ float hs[16][64];
  const int tid = threadIdx.x;
  const int n = blockIdx.x * 256 + tid;
  const int i0 = blockIdx.y * 64;
  for (int x = tid; x < 16 * 64; x += 256) {
    const int bb = x >> 6, ii = x & 63;
    hs[bb][ii] = fmaxf(hpre[bb * (4 * D_) + i0 + ii] + b1[i0 + ii], 0.0f);
  }
  __syncthreads();
  float acc[16] = {};
  for (int i = 0; i < 64; i++) {
    const float w = W2[(size_t)(i0 + i) * D_ + n];
#pragma unroll
    for (int bb = 0; bb < 16; bb++) acc[bb] += hs[bb][i] * w;
  }
#pragma unroll
  for (int bb = 0; bb < 16; bb++) atomicAdd(&outpre[bb * D_ + n], acc[bb]);
}

// ---------------- out = tanh(outpre + b2)
__global__ void k_finish(const float* __restrict__ outpre, const float* __restrict__ b2,
                         float* __restrict__ out) {
  const int x = blockIdx.x * 256 + threadIdx.x;
  out[x] = tanhf(outpre[x] + b2[x & (D_ - 1)]);
}

extern "C" void kernel_launch(void* const* d_in, const int* in_sizes, int n_in,
                              void* d_out, int out_size, void* d_ws, size_t ws_size,
                              hipStream_t stream) {
  const float* X  = (const float*)d_in[0];
  const int* mask = (const int*)d_in[1];
  const float* Wq = (const float*)d_in[2];
  const float* bq = (const float*)d_in[3];
  const float* Wk = (const float*)d_in[4];
  const float* bk = (const float*)d_in[5];
  const float* Wv = (const float*)d_in[6];
  const float* bv = (const float*)d_in[7];
  const float* W1 = (const float*)d_in[8];
  const float* b1 = (const float*)d_in[9];
  const float* W2 = (const float*)d_in[10];
  const float* b2 = (const float*)d_in[11];
  float* out = (float*)d_out;

  char* ws = (char*)d_ws;
  size_t off = 0;
  auto alloc = [&](size_t bytes) -> void* {
    void* p = ws + off;
    off += (bytes + 255) & ~(size_t)255;
    return p;
  };
  u16* Qb  = (u16*)alloc(BSD * sizeof(u16));                          // 64 MB
  u16* KVc = (u16*)alloc((size_t)2 * 16 * C_ * D_ * sizeof(u16));     // 80 MB (K_c | V_c)
  u16* Kc  = KVc;
  u16* Vc  = KVc + (size_t)16 * C_ * D_;
  u16* ScX = (u16*)alloc((size_t)16 * 2048 * C_ * sizeof(u16));       // 80 MB
  u16* Xb  = ScX;   // X-bf16 aliases Sc: consumed by Q/KV GEMMs before Sc written
  u16* Sc  = ScX;
  u16* Wt  = (u16*)alloc((size_t)3 * D_ * D_ * sizeof(u16));          // 6 MB
  float* biasQKV = (float*)alloc(3 * D_ * sizeof(float));
  int* map    = (int*)alloc((size_t)16 * C_ * sizeof(int));           // 80 KB
  int* counts = (int*)alloc(16 * sizeof(int));
  float* cpart  = (float*)alloc((size_t)32 * 16 * C_ * sizeof(float)); // 2.6 MB
  float* pooled = (float*)alloc((size_t)B_ * D_ * sizeof(float));
  float* hpre   = (float*)alloc((size_t)B_ * 4 * D_ * sizeof(float));
  float* outpre = (float*)alloc((size_t)B_ * D_ * sizeof(float));
  (void)ws_size; (void)in_sizes; (void)n_in; (void)out_size;

  const size_t zero_bytes = (size_t)B_ * D_ * 4 + (size_t)B_ * 4 * D_ * 4 +
                            (size_t)B_ * D_ * 4;
  hipMemsetAsync(pooled, 0, zero_bytes, stream);

  // fused prep: cvt_x (16384) + W transpose (3072) + bias (1) + mask scan (16)
  k_prep<<<16384 + 3089, 256, 0, stream>>>(X, Xb, Wq, Wk, Wv, bq, bk, bv,
                                           mask, Wt, biasQKV, map, counts);

  // merged Q + KV GEMM (R15): 512 + 640 = 1152 blocks
  k_gemm8<0><<<dim3(1152, 1, 1), 512, 131072, stream>>>(
      Xb, Wt, biasQKV, Qb, KVc, map, counts, 1.0f);

  // Sc[b,q,kc] = (Q[b,q,:] . K_c[b,kc,:]) / 32  (skip-tail; overwrites Xb alias)
  k_gemm8<2><<<dim3(C_ / 256, 8, 16), 512, 131072, stream>>>(
      Qb, Kc, nullptr, Sc, nullptr, nullptr, counts, 0.03125f);

  k_softmax_colsum<<<dim3(32, B_), 256, 0, stream>>>(Sc, counts, cpart);
  k_cv<<<dim3(C_ / 128, B_), 256, 0, stream>>>(cpart, Vc, pooled);
  k_mlp1<<<dim3(16, 16), 256, 0, stream>>>(pooled, W1, hpre);
  k_mlp2<<<dim3(4, 64), 256, 0, stream>>>(hpre, b1, W2, outpre);
  k_finish<<<64, 256, 0, stream>>>(outpre, b2, out);
}

// Round 18
// 389.180 us; speedup vs baseline: 1.0250x; 1.0030x over previous
//
#include <hip/hip_runtime.h>
#include <hip/hip_bf16.h>

constexpr int B_ = 16;
constexpr int S_ = 2048;
constexpr int D_ = 1024;
constexpr int C_ = 1280;                              // compacted K capacity (5*256)
constexpr long long BSD = (long long)B_ * S_ * D_;   // 33,554,432

typedef unsigned short u16;
typedef __bf16 bf16x8 __attribute__((ext_vector_type(8)));
typedef float    f32x4 __attribute__((ext_vector_type(4)));
typedef unsigned short usx8 __attribute__((ext_vector_type(8)));
typedef unsigned short usx4 __attribute__((ext_vector_type(4)));

__device__ inline u16 f2b(float f) {            // f32 -> bf16 RNE
  unsigned u = __float_as_uint(f);
  u = (u + 0x7fffu + ((u >> 16) & 1u)) >> 16;
  return (u16)u;
}
__device__ inline float b2f(u16 v) { return __uint_as_float(((unsigned)v) << 16); }

__device__ __forceinline__ void gll16(const void* g, void* l) {
  __builtin_amdgcn_global_load_lds(
      (const __attribute__((address_space(1))) void*)g,
      (__attribute__((address_space(3))) void*)l, 16, 0, 0);
}

__device__ __forceinline__ void vmwait4() {
  asm volatile("s_waitcnt vmcnt(4)" ::: "memory");
  __builtin_amdgcn_sched_barrier(0);
}
__device__ __forceinline__ void vmwait2() {
  asm volatile("s_waitcnt vmcnt(2)" ::: "memory");
  __builtin_amdgcn_sched_barrier(0);
}
__device__ __forceinline__ void vmwait0() {
  asm volatile("s_waitcnt vmcnt(0)" ::: "memory");
  __builtin_amdgcn_sched_barrier(0);
}
__device__ __forceinline__ void lgkm6() {
  asm volatile("s_waitcnt lgkmcnt(6)" ::: "memory");
  __builtin_amdgcn_sched_barrier(0);
}
__device__ __forceinline__ void lgkm4() {
  asm volatile("s_waitcnt lgkmcnt(4)" ::: "memory");
  __builtin_amdgcn_sched_barrier(0);
}
__device__ __forceinline__ void lgkm2() {
  asm volatile("s_waitcnt lgkmcnt(2)" ::: "memory");
  __builtin_amdgcn_sched_barrier(0);
}
__device__ __forceinline__ void lgkm0w() {
  asm volatile("s_waitcnt lgkmcnt(0)" ::: "memory");
  __builtin_amdgcn_sched_barrier(0);
}
__device__ __forceinline__ void sbar() { __builtin_amdgcn_sched_barrier(0); }
__device__ __forceinline__ void barrier_pin() {
  __builtin_amdgcn_sched_barrier(0);
  __builtin_amdgcn_s_barrier();
  __builtin_amdgcn_sched_barrier(0);
}

// ---------------- fused prep: X cvt (16384), W transpose+cvt (3072),
// bias pack (1), per-batch mask compaction scan (16) ----------------
__global__ __launch_bounds__(256) void k_prep(
    const float* __restrict__ X, u16* __restrict__ Xb,
    const float* __restrict__ Wq, const float* __restrict__ Wk, const float* __restrict__ Wv,
    const float* __restrict__ bq, const float* __restrict__ bk, const float* __restrict__ bv,
    const int* __restrict__ mask, u16* __restrict__ Wt,
    float* __restrict__ biasQKV, int* __restrict__ map, int* __restrict__ counts) {
  __shared__ float tile[32][33];
  __shared__ int ts[256];
  const int bid = blockIdx.x;
  const int tid = threadIdx.x;
  if (bid < 16384) {
    size_t i = ((size_t)bid * 256 + tid) * 8;
    f32x4 a = *(const f32x4*)(X + i);
    f32x4 b = *(const f32x4*)(X + i + 4);
    usx8 o;
    o[0] = f2b(a[0]); o[1] = f2b(a[1]); o[2] = f2b(a[2]); o[3] = f2b(a[3]);
    o[4] = f2b(b[0]); o[5] = f2b(b[1]); o[6] = f2b(b[2]); o[7] = f2b(b[3]);
    *(usx8*)(Xb + i) = o;
  } else if (bid < 16384 + 3072) {
    const int wb = bid - 16384;
    const int z = wb >> 10, t = wb & 1023;
    const float* W = (z == 0) ? Wq : (z == 1 ? Wk : Wv);
    u16* dst = Wt + (size_t)z * D_ * D_;
    const int n0 = (t & 31) * 32, k0 = (t >> 5) * 32;
    const int tx = tid & 31, ty = tid >> 5;
    for (int r = ty; r < 32; r += 8)
      tile[r][tx] = W[(size_t)(k0 + r) * D_ + n0 + tx];
    __syncthreads();
    for (int r = ty; r < 32; r += 8)
      dst[(size_t)(n0 + r) * D_ + k0 + tx] = f2b(tile[tx][r]);
  } else if (bid == 16384 + 3072) {
    for (int x = tid; x < 3072; x += 256)
      biasQKV[x] = (x < 1024) ? bq[x] : (x < 2048 ? bk[x - 1024] : bv[x - 2048]);
  } else {
    const int b = bid - (16384 + 3073);
    const int* mrow = mask + b * S_;
    int lv[8]; int s = 0;
#pragma unroll
    for (int j = 0; j < 8; ++j) { lv[j] = (mrow[tid * 8 + j] != 0) ? 1 : 0; s += lv[j]; }
    ts[tid] = s;
    __syncthreads();
    for (int off = 1; off < 256; off <<= 1) {
      int v = (tid >= off) ? ts[tid - off] : 0;
      __syncthreads();
      ts[tid] += v;
      __syncthreads();
    }
    int pos = ts[tid] - s;                        // exclusive prefix
#pragma unroll
    for (int j = 0; j < 8; ++j) if (lv[j]) map[b * C_ + (pos++)] = tid * 8 + j;
    const int nb = ts[255];
    if (tid == 0) counts[b] = nb;
    for (int x = nb + tid; x < C_; x += 256) map[b * C_ + x] = 0;   // pads -> row 0
  }
}

// =====================================================================
// 256x256 GEMM (B-transposed), K=1024, BK=64, dbuf ring-2 — EXACT R15
// (best proven). R6 barrier skeleton (8 barriers/tile) + R6 vmcnt
// ledger + kk-split counted lgkm with emission order pinned by
// sched_barrier between kk groups.
// vmcnt ledger: stages (t+1): P0:A0 P1:B0 P2:B1 P3:A1; vmwait4 certs:
//   P3(t-1)->P0(t) reads, P0->B1, P1->A1, P2 none. Tail: 2/0/-/-.
//   MODE 0 (merged Q+KV): 1D grid 1152; tl<512 -> Q; else KV (gather
//     via map; skip-tail).  MODE 2 (SCORES): skip-tail via counts.
// LDS swizzle: phys_slot = logical ^ (row&7), both-sides (conflicts=0).
// =====================================================================
#define READ_A_K(DD, MQ, KK)                                              \
  _Pragma("unroll")                                                       \
  for (int f = 0; f < 4; ++f)                                             \
    a_[f][KK] = *(const bf16x8*)(sm + (((DD) + (MQ) * 8192 + A_pre + f * 1024) ^ ((KK) * 32)));

#define READ_B_K(DD, NQ, KK)                                              \
  _Pragma("unroll")                                                       \
  for (int n = 0; n < 2; ++n)                                             \
    b_[NQ][n][KK] = *(const bf16x8*)(sm + (((DD) + 16384 + (NQ) * 8192 + B_pre + n * 1024) ^ ((KK) * 32)));

#define MFMA_H(IO, JO, BQ, KK)                                            \
  __builtin_amdgcn_s_setprio(1);                                          \
  _Pragma("unroll")                                                       \
  for (int f = 0; f < 4; ++f)                                             \
    _Pragma("unroll")                                                     \
    for (int n = 0; n < 2; ++n)                                           \
      acc[(IO) + f][(JO) + n] = __builtin_amdgcn_mfma_f32_16x16x32_bf16(  \
          a_[f][KK], b_[BQ][n][KK], acc[(IO) + f][(JO) + n], 0, 0, 0);    \
  __builtin_amdgcn_s_setprio(0);

template <int MODE>
__global__ __launch_bounds__(512, 2) void k_gemm8(
    const u16* __restrict__ A, const u16* __restrict__ Bt,
    const float* __restrict__ bias, u16* __restrict__ C, u16* __restrict__ C2,
    const int* __restrict__ map, const int* __restrict__ counts, float scale) {
  extern __shared__ u16 sm[];            // 2 dbuf * 4 parts * 8192 u16 = 128 KiB
  constexpr int NT = 16;                 // 1024 / 64
  const int tid = threadIdx.x, lane = tid & 63, wave = tid >> 6;

  // XCD-aware bijective swizzle (nwg % 8 == 0 for both grids)
  const int gx = gridDim.x, gy = gridDim.y;
  const int nwg = gx * gy * gridDim.z;
  const int orig = blockIdx.x + gx * (blockIdx.y + gy * blockIdx.z);
  const int cpx = nwg >> 3;
  const int tl = (orig & 7) * cpx + (orig >> 3);

  const u16* Az; const u16* Bz;
  int batch = 0, mtile = 0, bx, by;
  bool isQ = false;
  if constexpr (MODE == 0) {
    if (tl < 512) {            // Q sub-job
      isQ = true;
      bx = tl & 3; by = tl >> 2;
      Az = A; Bz = Bt;
    } else {                   // KV sub-job
      const int i = tl - 512;
      bx = i & 7; by = i >> 3;
      batch = by / 5; mtile = by - batch * 5;
      if (mtile * 256 >= counts[batch]) return;    // dead compacted tile
      Az = A + (size_t)batch * S_ * D_;
      Bz = Bt + (size_t)D_ * D_;                   // Wt_kv (2048 rows)
    }
  } else {
    bx = tl % gx;
    const int rest = tl / gx;
    by = rest % gy;
    batch = rest / gy;
    if (bx * 256 >= counts[batch]) return;         // dead compacted col-tile
    Az = A + (size_t)batch * S_ * D_;
    Bz = Bt + (size_t)batch * C_ * D_;
  }
  const int wm_i = wave >> 2, wn_i = wave & 3;
  const int n0 = bx * 256;

  // ---- staging pointers (pre-swizzled global source; linear gll dest) ----
  const int grow = tid >> 3;                                   // 0..63
  const int gslot = ((tid & 7) ^ ((tid >> 3) & 7)) * 8;        // u16
  const u16 *pAa0, *pAb0, *pAa1, *pAb1;
  if (MODE == 0 && !isQ) {
    const int* mp = map + batch * C_ + mtile * 256;
    pAa0 = Az + (size_t)mp[grow] * D_ + gslot;
    pAb0 = Az + (size_t)mp[grow + 64] * D_ + gslot;
    pAa1 = Az + (size_t)mp[grow + 128] * D_ + gslot;
    pAb1 = Az + (size_t)mp[grow + 192] * D_ + gslot;
  } else {
    const int m0 = by * 256;
    pAa0 = Az + (size_t)(m0 + grow) * D_ + gslot;
    pAb0 = pAa0 + (size_t)64 * D_;
    pAa1 = pAa0 + (size_t)128 * D_;
    pAb1 = pAa0 + (size_t)192 * D_;
  }
  const u16* pBa0 = Bz + (size_t)(n0 + grow) * D_ + gslot;
  const u16* pBb0 = pBa0 + (size_t)64 * D_;
  const u16* pBa1 = pBa0 + (size_t)128 * D_;
  const u16* pBb1 = pBa0 + (size_t)192 * D_;

  // parts: 0=A0 1=A1 2=B0 3=B1 (LDS offset part*8192)
  auto stage_part = [&](int t, int part) {
    const u16* ga = (part == 0) ? pAa0 : (part == 1) ? pAa1 : (part == 2) ? pBa0 : pBa1;
    const u16* gb = (part == 0) ? pAb0 : (part == 1) ? pAb1 : (part == 2) ? pBb0 : pBb1;
    u16* l0 = sm + (t & 1) * 32768 + part * 8192 + wave * 512;
    gll16(ga + t * 64, l0);
    gll16(gb + t * 64, l0 + 4096);
  };

  // ---- read offsets (u16): phys_slot = logical ^ (row&7) ----
  const int r16 = lane & 15;
  const int s0k = (lane >> 4) ^ (lane & 7);
  const int A_pre = wm_i * 4096 + r16 * 64 + s0k * 8;   // + MQ*8192 + f*1024
  const int B_pre = wn_i * 2048 + r16 * 64 + s0k * 8;   // + 16384 + NQ*8192 + n*1024

  f32x4 acc[8][4] = {};
  bf16x8 a_[4][2], b_[2][2][2];

  // prologue: stage tile 0 in ledger order A0,B0,B1,A1; certify {A0,B0}
  stage_part(0, 0); stage_part(0, 2); stage_part(0, 3); stage_part(0, 1);
  vmwait4();
  barrier_pin();

#pragma unroll 1
  for (int t = 0; t < NT - 1; ++t) {
    const int DD = (t & 1) * 32768;
    // ---- P0: reads A0,B0 (kk0 pinned first); stage A0(t+1); certify B1(t)
    READ_A_K(DD, 0, 0) READ_B_K(DD, 0, 0)
    sbar();
    READ_A_K(DD, 0, 1) READ_B_K(DD, 0, 1)
    sbar();
    stage_part(t + 1, 0);
    vmwait4(); barrier_pin();
    lgkm6();  MFMA_H(0, 0, 0, 0)
    lgkm0w(); MFMA_H(0, 0, 0, 1)
    barrier_pin();
    // ---- P1: reads B1 (kk-split); stage B0(t+1); certify A1(t)
    READ_B_K(DD, 1, 0)
    sbar();
    READ_B_K(DD, 1, 1)
    sbar();
    stage_part(t + 1, 2);
    vmwait4(); barrier_pin();
    lgkm2();  MFMA_H(0, 2, 1, 0)
    lgkm0w(); MFMA_H(0, 2, 1, 1)
    barrier_pin();
    // ---- P2: reads A1 (kk-split); stage B1(t+1); no vm wait
    READ_A_K(DD, 1, 0)
    sbar();
    READ_A_K(DD, 1, 1)
    sbar();
    stage_part(t + 1, 3);
    barrier_pin();
    lgkm4();  MFMA_H(4, 2, 1, 0)
    lgkm0w(); MFMA_H(4, 2, 1, 1)
    barrier_pin();
    // ---- P3: no reads; stage A1(t+1); certify {A0,B0}(t+1)
    stage_part(t + 1, 1);
    vmwait4(); barrier_pin();
    MFMA_H(4, 0, 0, 0) MFMA_H(4, 0, 0, 1)
    barrier_pin();
  }
  {  // ---- tail tile (no stages)
    const int DD = ((NT - 1) & 1) * 32768;
    READ_A_K(DD, 0, 0) READ_B_K(DD, 0, 0)
    sbar();
    READ_A_K(DD, 0, 1) READ_B_K(DD, 0, 1)
    sbar();
    vmwait2(); barrier_pin();
    lgkm6();  MFMA_H(0, 0, 0, 0)
    lgkm0w(); MFMA_H(0, 0, 0, 1)
    barrier_pin();
    READ_B_K(DD, 1, 0)
    sbar();
    READ_B_K(DD, 1, 1)
    sbar();
    vmwait0(); barrier_pin();
    lgkm2();  MFMA_H(0, 2, 1, 0)
    lgkm0w(); MFMA_H(0, 2, 1, 1)
    barrier_pin();
    READ_A_K(DD, 1, 0)
    sbar();
    READ_A_K(DD, 1, 1)
    sbar();
    barrier_pin();
    lgkm4();  MFMA_H(4, 2, 1, 0)
    lgkm0w(); MFMA_H(4, 2, 1, 1)
    barrier_pin();
    MFMA_H(4, 0, 0, 0) MFMA_H(4, 0, 0, 1)
  }

  // epilogue: C/D layout col = lane&15, row = (lane>>4)*4 + r
#pragma unroll
  for (int i = 0; i < 8; ++i) {
    const int MQ = i >> 2, f = i & 3;
    const int lrow = MQ * 128 + wm_i * 64 + f * 16 + ((lane >> 4) << 2);
#pragma unroll
    for (int j = 0; j < 4; ++j) {
      const int NQ = j >> 1, n = j & 1;
      const int col = n0 + NQ * 128 + wn_i * 32 + n * 16 + (lane & 15);
      if constexpr (MODE == 0) {
        if (isQ) {
          const float badd = bias[col];
          u16* cp = C + (size_t)(by * 256 + lrow) * 1024 + col;
#pragma unroll
          for (int r = 0; r < 4; ++r) cp[(size_t)r * 1024] = f2b(acc[i][j][r] + badd);
        } else {
          const float badd = bias[1024 + col];
          u16* cp = C2 + (size_t)(col >> 10) * ((size_t)16 * C_ * 1024)
                      + ((size_t)batch * C_ + mtile * 256 + lrow) * 1024 + (col & 1023);
#pragma unroll
          for (int r = 0; r < 4; ++r) cp[(size_t)r * 1024] = f2b(acc[i][j][r] + badd);
        }
      } else {
        u16* cp = C + ((size_t)batch * 2048 + by * 256 + lrow) * C_ + col;
#pragma unroll
        for (int r = 0; r < 4; ++r) cp[(size_t)r * C_] = f2b(acc[i][j][r] * scale);
      }
    }
  }
}

// ---------------- softmax rows + column-sum partials over compacted cols
// grid (32, 16): block = 64 q-rows of batch b; writes cpart[b*32+bi][0..C_)
// Fast paths: full16 lanes skip bound checks; c4 region [1024,1280)
// skipped entirely when c4 >= nb (uniform for nb <= 1024).
__global__ __launch_bounds__(256) void k_softmax_colsum(
    const u16* __restrict__ Sc, const int* __restrict__ counts,
    float* __restrict__ cpart) {
  __shared__ float colsum[C_];
  const int b = blockIdx.y, bi = blockIdx.x;
  const int tid = threadIdx.x, lane = tid & 63, wave = tid >> 6;
  for (int k = tid; k < C_; k += 256) colsum[k] = 0.0f;
  __syncthreads();

  const int nb = counts[b];
  const u16* base = Sc + ((size_t)b * 2048 + bi * 64 + wave * 16) * C_;
  const int c16 = lane * 16;          // cols [c16, c16+16)
  const int c4 = 1024 + lane * 4;     // cols [c4, c4+4)
  const bool full16 = (c16 + 16 <= nb);
  const bool has4   = (c4 < nb);
  const bool full4  = (c4 + 4 <= nb);
  float csum[20];
#pragma unroll
  for (int i = 0; i < 20; i++) csum[i] = 0.0f;

  for (int rr = 0; rr < 16; rr++) {
    const u16* srow = base + (size_t)rr * C_;
    usx8 x0 = *(const usx8*)(srow + c16);
    usx8 x1 = *(const usx8*)(srow + c16 + 8);
    float s[20];
    float m = -1e30f;
    if (full16) {
#pragma unroll
      for (int e = 0; e < 8; e++) {
        s[e] = b2f(x0[e]);
        s[8 + e] = b2f(x1[e]);
        m = fmaxf(m, fmaxf(s[e], s[8 + e]));
      }
    } else {
#pragma unroll
      for (int e = 0; e < 8; e++) {
        s[e] = (c16 + e < nb) ? b2f(x0[e]) : -1e30f;
        s[8 + e] = (c16 + 8 + e < nb) ? b2f(x1[e]) : -1e30f;
        m = fmaxf(m, fmaxf(s[e], s[8 + e]));
      }
    }
    if (has4) {
      usx4 x2 = *(const usx4*)(srow + c4);
      if (full4) {
#pragma unroll
        for (int e = 0; e < 4; e++) { s[16 + e] = b2f(x2[e]); m = fmaxf(m, s[16 + e]); }
      } else {
#pragma unroll
        for (int e = 0; e < 4; e++) {
          s[16 + e] = (c4 + e < nb) ? b2f(x2[e]) : -1e30f;
          m = fmaxf(m, s[16 + e]);
        }
      }
    }
#pragma unroll
    for (int o = 1; o < 64; o <<= 1) m = fmaxf(m, __shfl_xor(m, o));
    float sum = 0.f;
#pragma unroll
    for (int i = 0; i < 16; i++) { s[i] = __expf(s[i] - m); sum += s[i]; }
    if (has4) {
#pragma unroll
      for (int i = 16; i < 20; i++) { s[i] = __expf(s[i] - m); sum += s[i]; }
    }
#pragma unroll
    for (int o = 1; o < 64; o <<= 1) sum += __shfl_xor(sum, o);
    const float inv = 1.0f / (sum * (float)S_);
#pragma unroll
    for (int i = 0; i < 16; i++) csum[i] += s[i] * inv;
    if (has4) {
#pragma unroll
      for (int i = 16; i < 20; i++) csum[i] += s[i] * inv;
    }
  }
#pragma unroll
  for (int i = 0; i < 16; i++) {
    const int e = (i + lane) & 15;
    atomicAdd(&colsum[c16 + e], csum[e]);
  }
  if (has4) {
#pragma unroll
    for (int i = 0; i < 4; i++) {
      const int e = (i + lane) & 3;
      atomicAdd(&colsum[c4 + e], csum[16 + e]);
    }
  }
  __syncthreads();
  float* dst = cpart + ((size_t)b * 32 + bi) * C_;
  for (int k = tid; k < C_; k += 256) dst[k] = colsum[k];
}

// ---------------- pooled[b,d] += sum_{kc in slice} c[b,kc] * V_c[b,kc,d]
// grid (C_/64 = 20, 16): 64-k slices for 2x parallelism
__global__ __launch_bounds__(256) void k_cv(const float* __restrict__ cpart,
                                            const u16* __restrict__ Vc,
                                            float* __restrict__ pooled) {
  __shared__ float cl[64];
  const int b = blockIdx.y;
  const int k0 = blockIdx.x * 64;
  const int tid = threadIdx.x;
  if (tid < 64) {
    float s = 0.f;
    const float* p = cpart + (size_t)b * 32 * C_ + k0 + tid;
#pragma unroll 4
    for (int q = 0; q < 32; q++) s += p[(size_t)q * C_];
    cl[tid] = s;
  }
  __syncthreads();
  f32x4 acc = {};
  const u16* vb = Vc + ((size_t)b * C_ + k0) * 1024 + tid * 4;
  for (int k = 0; k < 64; k++) {
    const float w = cl[k];
    usx4 v = *(const usx4*)(vb + (size_t)k * 1024);
    acc[0] += w * b2f(v[0]);
    acc[1] += w * b2f(v[1]);
    acc[2] += w * b2f(v[2]);
    acc[3] += w * b2f(v[3]);
  }
#pragma unroll
  for (int q = 0; q < 4; q++) atomicAdd(&pooled[b * D_ + tid * 4 + q], acc[q]);
}

// ---------------- hpre = pooled @ W1 (atomic K-split, grid (16,16))
__global__ __launch_bounds__(256) void k_mlp1(const float* __restrict__ pooled,
                                              const float* __restrict__ W1,
                                              float* __restrict__ hpre) {
  __shared__ float ps[16][64];
  const int tid = threadIdx.x;
  const int j = blockIdx.x * 256 + tid;
  const int i0 = blockIdx.y * 64;
  for (int x = tid; x < 16 * 64; x += 256) {
    const int bb = x >> 6, ii = x & 63;
    ps[bb][ii] = pooled[bb * D_ + i0 + ii];
  }
  __syncthreads();
  float acc[16] = {};
  for (int i = 0; i < 64; i++) {
    const float w = W1[(size_t)(i0 + i) * (4 * D_) + j];
#pragma unroll
    for (int bb = 0; bb < 16; bb++) acc[bb] += ps[bb][i] * w;
  }
#pragma unroll
  for (int bb = 0; bb < 16; bb++) atomicAdd(&hpre[bb * (4 * D_) + j], acc[bb]);
}

// ---------------- outpre = relu(hpre + b1) @ W2 (atomic K-split, grid (4,64))
__global__ __launch_bounds__(256) void k_mlp2(const float* __restrict__ hpre,
                                              const float* __restrict__ b1,
                                              const float* __restrict__ W2,
                                              float* __restrict__ outpre) {
  __shared__ float hs[16][64];
  const int tid = threadIdx.x;
  const int n = blockIdx.x * 256 + tid;
  const int i0 = blockIdx.y * 64;
  for (int x = tid; x < 16 * 64; x += 256) {
    const int bb = x >> 6, ii = x & 63;
    hs[bb][ii] = fmaxf(hpre[bb * (4 * D_) + i0 + ii] + b1[i0 + ii], 0.0f);
  }
  __syncthreads();
  float acc[16] = {};
  for (int i = 0; i < 64; i++) {
    const float w = W2[(size_t)(i0 + i) * D_ + n];
#pragma unroll
    for (int bb = 0; bb < 16; bb++) acc[bb] += hs[bb][i] * w;
  }
#pragma unroll
  for (int bb = 0; bb < 16; bb++) atomicAdd(&outpre[bb * D_ + n], acc[bb]);
}

// ---------------- out = tanh(outpre + b2)
__global__ void k_finish(const float* __restrict__ outpre, const float* __restrict__ b2,
                         float* __restrict__ out) {
  const int x = blockIdx.x * 256 + threadIdx.x;
  out[x] = tanhf(outpre[x] + b2[x & (D_ - 1)]);
}

extern "C" void kernel_launch(void* const* d_in, const int* in_sizes, int n_in,
                              void* d_out, int out_size, void* d_ws, size_t ws_size,
                              hipStream_t stream) {
  const float* X  = (const float*)d_in[0];
  const int* mask = (const int*)d_in[1];
  const float* Wq = (const float*)d_in[2];
  const float* bq = (const float*)d_in[3];
  const float* Wk = (const float*)d_in[4];
  const float* bk = (const float*)d_in[5];
  const float* Wv = (const float*)d_in[6];
  const float* bv = (const float*)d_in[7];
  const float* W1 = (const float*)d_in[8];
  const float* b1 = (const float*)d_in[9];
  const float* W2 = (const float*)d_in[10];
  const float* b2 = (const float*)d_in[11];
  float* out = (float*)d_out;

  char* ws = (char*)d_ws;
  size_t off = 0;
  auto alloc = [&](size_t bytes) -> void* {
    void* p = ws + off;
    off += (bytes + 255) & ~(size_t)255;
    return p;
  };
  u16* Qb  = (u16*)alloc(BSD * sizeof(u16));                          // 64 MB
  u16* KVc = (u16*)alloc((size_t)2 * 16 * C_ * D_ * sizeof(u16));     // 80 MB (K_c | V_c)
  u16* Kc  = KVc;
  u16* Vc  = KVc + (size_t)16 * C_ * D_;
  u16* ScX = (u16*)alloc((size_t)16 * 2048 * C_ * sizeof(u16));       // 80 MB
  u16* Xb  = ScX;   // X-bf16 aliases Sc: consumed by Q/KV GEMMs before Sc written
  u16* Sc  = ScX;
  u16* Wt  = (u16*)alloc((size_t)3 * D_ * D_ * sizeof(u16));          // 6 MB
  float* biasQKV = (float*)alloc(3 * D_ * sizeof(float));
  int* map    = (int*)alloc((size_t)16 * C_ * sizeof(int));           // 80 KB
  int* counts = (int*)alloc(16 * sizeof(int));
  float* cpart  = (float*)alloc((size_t)32 * 16 * C_ * sizeof(float)); // 2.6 MB
  float* pooled = (float*)alloc((size_t)B_ * D_ * sizeof(float));
  float* hpre   = (float*)alloc((size_t)B_ * 4 * D_ * sizeof(float));
  float* outpre = (float*)alloc((size_t)B_ * D_ * sizeof(float));
  (void)ws_size; (void)in_sizes; (void)n_in; (void)out_size;

  const size_t zero_bytes = (size_t)B_ * D_ * 4 + (size_t)B_ * 4 * D_ * 4 +
                            (size_t)B_ * D_ * 4;
  hipMemsetAsync(pooled, 0, zero_bytes, stream);

  // fused prep: cvt_x (16384) + W transpose (3072) + bias (1) + mask scan (16)
  k_prep<<<16384 + 3089, 256, 0, stream>>>(X, Xb, Wq, Wk, Wv, bq, bk, bv,
                                           mask, Wt, biasQKV, map, counts);

  // merged Q + KV GEMM (R15): 512 + 640 = 1152 blocks
  k_gemm8<0><<<dim3(1152, 1, 1), 512, 131072, stream>>>(
      Xb, Wt, biasQKV, Qb, KVc, map, counts, 1.0f);

  // Sc[b,q,kc] = (Q[b,q,:] . K_c[b,kc,:]) / 32  (skip-tail; overwrites Xb alias)
  k_gemm8<2><<<dim3(C_ / 256, 8, 16), 512, 131072, stream>>>(
      Qb, Kc, nullptr, Sc, nullptr, nullptr, counts, 0.03125f);

  k_softmax_colsum<<<dim3(32, B_), 256, 0, stream>>>(Sc, counts, cpart);
  k_cv<<<dim3(C_ / 64, B_), 256, 0, stream>>>(cpart, Vc, pooled);
  k_mlp1<<<dim3(16, 16), 256, 0, stream>>>(pooled, W1, hpre);
  k_mlp2<<<dim3(4, 64), 256, 0, stream>>>(hpre, b1, W2, outpre);
  k_finish<<<64, 256, 0, stream>>>(outpre, b2, out);
}